// Round 19
// baseline (162.880 us; speedup 1.0000x reference)
//
#include <hip/hip_runtime.h>

#define N_ENT 50000
#define MPAD  50048            // 391*128, padded rows for GEMM staging
#define N_RELS 500
#define DD 256
#define HD 128
#define EPD 250000
#define ETOT 500000
#define NK (2 * N_ENT)         // (dir,row) keys
#define NBLK 98                // ceil(NK/1024)
#define REL_SCALE 2.0943951023931953f  // pi / 1.5

typedef unsigned short ushort_t;
typedef unsigned int uint_t;
typedef __attribute__((ext_vector_type(2))) _Float16 h2;
typedef __attribute__((ext_vector_type(8))) _Float16 h8;
typedef __attribute__((ext_vector_type(2))) float f32x2;
typedef __attribute__((ext_vector_type(4))) float f32x4;
typedef __attribute__((ext_vector_type(4))) uint_t u32x4;

#if __has_builtin(__builtin_amdgcn_cvt_pk_f32_fp8) && __has_builtin(__builtin_amdgcn_cvt_pk_fp8_f32)
#define USE_FP8 1
#else
#define USE_FP8 0
#endif

__device__ inline uint_t pkh2(float a, float b) {
    union { _Float16 h[2]; uint_t u; } v;
    v.h[0] = (_Float16)a; v.h[1] = (_Float16)b; return v.u;
}
__device__ inline h2 bch2(uint_t w) {
    union { uint_t u; h2 h; } v; v.u = w; return v.h;
}

#if __has_builtin(__builtin_amdgcn_fdot2)
#define FDOT2(a, b, c) __builtin_amdgcn_fdot2((a), (b), (c), false)
#else
__device__ inline float FDOT2(h2 a, h2 b, float c) {
    return c + (float)a[0] * (float)b[0] + (float)a[1] * (float)b[1];
}
#endif

#define GLOAD_LDS16(g, l) __builtin_amdgcn_global_load_lds( \
    (const __attribute__((address_space(1))) unsigned int*)(g), \
    (__attribute__((address_space(3))) unsigned int*)(l), 16, 0, 0)

// ---------------- per-block exclusive scan + dinv (98 blocks) --------------
__global__ __launch_bounds__(256) void k_scan1(const int* __restrict__ deg,
                                               int* __restrict__ off,
                                               int* __restrict__ bsum,
                                               float* __restrict__ dinv) {
    __shared__ int wsum[4];
    int b = blockIdx.x, t = threadIdx.x;
    int base = b * 1024 + t * 4;
    int v[4];
#pragma unroll
    for (int i = 0; i < 4; ++i) v[i] = (base + i < NK) ? deg[base + i] : 0;
    int tsum = v[0] + v[1] + v[2] + v[3];
    int lane = t & 63, w = t >> 6;
    int incl = tsum;
    for (int d = 1; d < 64; d <<= 1) {
        int y = __shfl_up(incl, d);
        if (lane >= d) incl += y;
    }
    if (lane == 63) wsum[w] = incl;
    __syncthreads();
    int woff = 0;
    for (int k = 0; k < w; ++k) woff += wsum[k];
    int run = woff + incl - tsum;
#pragma unroll
    for (int i = 0; i < 4; ++i) {
        if (base + i < NK) {
            off[base + i] = run;
            dinv[base + i] = (v[i] > 0) ? rsqrtf((float)v[i]) : 0.0f;
        }
        run += v[i];
    }
    if (t == 255) bsum[b] = woff + incl;   // block total
}

__global__ void k_scan2(int* __restrict__ bsum) {
    __shared__ int s[NBLK];
    int t = threadIdx.x;
    if (t < NBLK) s[t] = bsum[t];
    __syncthreads();
    if (t == 0) {
        int c = 0;
        for (int i = 0; i < NBLK; ++i) { int x = s[i]; s[i] = c; c += x; }
    }
    __syncthreads();
    if (t < NBLK) bsum[t] = s[t];
}

// ---------------- bucket edges: 8B entry {col|t<<16, f32 norm} -------------
__global__ __launch_bounds__(256) void k_bucket(const int* __restrict__ ei,
                                                const int* __restrict__ et,
                                                const int* __restrict__ off,
                                                const int* __restrict__ bsum,
                                                const float* __restrict__ dinv,
                                                int* __restrict__ cnt,
                                                uint2* __restrict__ ent) {
    int e = blockIdx.x * 256 + threadIdx.x;
    if (e >= ETOT) return;
    int dir = (e >= EPD);
    int key = dir * N_ENT + ei[e];
    int pos = off[key] + bsum[key >> 10] + atomicAdd(cnt + key, 1);
    int col = ei[ETOT + e];
    int t   = et[e];
    float nm = dinv[key] * dinv[dir * N_ENT + col];
    ent[pos] = make_uint2((uint_t)col | ((uint_t)t << 16), __float_as_uint(nm));
}

// ---------------- prepx: xc + xq, 4 chunks/thread for MLP (1600 blocks) ----
// chunk ci: col = ci>>5, pairs q=(ci&31)*4 .. +3
// xc[col*128 + p] = pack_f16(x[col][p], x[col][p+128])      (for GEMM)
// xq[col*64 + w]  = fp8 {re(2w), im(2w), re(2w+1), im(2w+1)} (for gather)
// All 8 loads issued before any store -> 8 HBM transactions in flight/thread.
__global__ __launch_bounds__(256) void k_prepx(const float* __restrict__ x,
                                               uint_t* __restrict__ xc,
                                               uint_t* __restrict__ xq) {
    int t0 = blockIdx.x * 256 + threadIdx.x;   // 0..409599
    f32x4 re0, re1, re2, re3, im0, im1, im2, im3;
    int c0, c1, c2, c3;
#define LOADU(U, RE, IM, CI) do {                                   \
        int c_ = t0 + (U) * 409600;                                 \
        CI = (c_ < 1600000) ? c_ : 1599999;                         \
        int col_ = CI >> 5, q_ = (CI & 31) << 2;                    \
        const f32x4* xr_ = (const f32x4*)(x + (size_t)col_ * DD);   \
        RE = xr_[q_ >> 2];                                          \
        IM = xr_[(q_ + HD) >> 2];                                   \
    } while (0)
    LOADU(0, re0, im0, c0);
    LOADU(1, re1, im1, c1);
    LOADU(2, re2, im2, c2);
    LOADU(3, re3, im3, c3);
#undef LOADU
#define STOREU(RE, IM, CI) do {                                     \
        int col_ = CI >> 5, q_ = (CI & 31) << 2;                    \
        u32x4 o_;                                                   \
        o_.x = pkh2(RE.x, IM.x);                                    \
        o_.y = pkh2(RE.y, IM.y);                                    \
        o_.z = pkh2(RE.z, IM.z);                                    \
        o_.w = pkh2(RE.w, IM.w);                                    \
        *(u32x4*)(xc + (size_t)col_ * HD + q_) = o_;                \
        int w0_ = __builtin_amdgcn_cvt_pk_fp8_f32(RE.x, IM.x, 0, 0);\
        w0_     = __builtin_amdgcn_cvt_pk_fp8_f32(RE.y, IM.y, w0_, 1);\
        int w1_ = __builtin_amdgcn_cvt_pk_fp8_f32(RE.z, IM.z, 0, 0);\
        w1_     = __builtin_amdgcn_cvt_pk_fp8_f32(RE.w, IM.w, w1_, 1);\
        *(uint2*)(xq + (size_t)col_ * 64 + (q_ >> 1)) =             \
            make_uint2((uint_t)w0_, (uint_t)w1_);                   \
    } while (0)
#if USE_FP8
    STOREU(re0, im0, c0);
    STOREU(re1, im1, c1);
    STOREU(re2, im2, c2);
    STOREU(re3, im3, c3);
#else
    // f16-only fallback (xq unused; gather falls back to xc path)
#define STOREH(RE, IM, CI) do {                                     \
        int col_ = CI >> 5, q_ = (CI & 31) << 2;                    \
        u32x4 o_;                                                   \
        o_.x = pkh2(RE.x, IM.x);                                    \
        o_.y = pkh2(RE.y, IM.y);                                    \
        o_.z = pkh2(RE.z, IM.z);                                    \
        o_.w = pkh2(RE.w, IM.w);                                    \
        *(u32x4*)(xc + (size_t)col_ * HD + q_) = o_;                \
    } while (0)
    STOREH(re0, im0, c0);
    STOREH(re1, im1, c1);
    STOREH(re2, im2, c2);
    STOREH(re3, im3, c3);
#undef STOREH
#endif
#undef STOREU
}

// ---- preps: utab (250) + Wt/3 (768) + relout (250) + deg4 (489) = 1757 ----
__global__ __launch_bounds__(256) void k_preps(const float* __restrict__ rel,
                                               const float* __restrict__ w_in,
                                               const float* __restrict__ w_out,
                                               const float* __restrict__ w_loop,
                                               const float* __restrict__ loop_rel,
                                               const float* __restrict__ w_rel,
                                               const int* __restrict__ ei,
                                               uint_t* __restrict__ utab,
                                               ushort_t* __restrict__ Wt,
                                               float* __restrict__ rel_out,
                                               int* __restrict__ deg) {
    int b = blockIdx.x, tid = threadIdx.x;
    if (b < 250) {                         // utab (cs only)
        int idx = b * 256 + tid;           // < 64000 = 500*128
        float s, c;
        __sincosf(rel[idx] * REL_SCALE, &s, &c);
        utab[idx] = pkh2(c, s);
    } else if (b < 1018) {                 // Wt[256n][768k] f16, /3 folded
        int idx = (b - 250) * 256 + tid;   // < 196608
        int n = idx / 768, k = idx - n * 768;
        float v;
        if (k < 256) {
            v = w_in[k * 256 + n];
        } else if (k < 512) {
            v = w_out[(k - 256) * 256 + n];
        } else {
            // third A-block is xc (interleaved): kk=2p -> x[p], kk=2p+1 -> x[p+128]
            int kk = k - 512;
            int jj = kk >> 1;
            float s, c;
            __sincosf(loop_rel[jj] * REL_SCALE, &s, &c);
            float w0 = w_loop[jj * 256 + n];
            float w1 = w_loop[(jj + HD) * 256 + n];
            v = ((kk & 1) == 0) ? (c * w0 + s * w1) : (s * w0 - c * w1);
        }
        union { _Float16 h; ushort_t u; } cv; cv.h = (_Float16)(v * (1.0f / 3.0f));
        Wt[idx] = cv.u;
    } else if (b < 1268) {                 // rel_out = rel_embed @ w_rel
        int idx = (b - 1018) * 256 + tid;  // < 64000
        int i = idx >> 7, c = idx & 127;
        float acc = 0.0f;
        for (int k = 0; k < HD; ++k) acc += rel[i * HD + k] * w_rel[k * HD + c];
        rel_out[idx] = acc;
    } else {                               // degree histogram, 4 edges/thread
        int e4 = ((b - 1268) * 256 + tid) * 4;   // < 500000
        if (e4 < ETOT) {
            int4 r4 = *(const int4*)(ei + e4);
#pragma unroll
            for (int q = 0; q < 4; ++q) {
                int e = e4 + q;
                int rv = (q == 0) ? r4.x : (q == 1) ? r4.y : (q == 2) ? r4.z : r4.w;
                if (e < ETOT) {
                    int key = (e >= EPD ? N_ENT : 0) + rv;
                    atomicAdd(deg + key, 1);
                }
            }
        }
    }
}

// ---------------- gather: one wave per (dir,row), 2 pairs per lane ---------
//   out_lo[j] = (re,im).(c,s)   -> A elem j
//   out_hi[j] = (re,im).(s,-c)  -> A elem j+128
// fp8 path: 4B/lane x-row load, v_cvt_pk_f32_fp8 decode, f32 FMA math.
__global__ __launch_bounds__(256) void k_gather(const uint2* __restrict__ ent,
                                                const int* __restrict__ off,
                                                const int* __restrict__ bsum,
                                                const int* __restrict__ deg,
                                                const uint_t* __restrict__ xq,
                                                const uint_t* __restrict__ xc,
                                                const uint_t* __restrict__ utab,
                                                ushort_t* __restrict__ A) {
    int wid  = (blockIdx.x * 256 + threadIdx.x) >> 6;
    int lane = threadIdx.x & 63;
    if (wid >= NK) return;
    int dir = (wid >= N_ENT);
    int row = wid - dir * N_ENT;
    int start = __builtin_amdgcn_readfirstlane(off[wid] + bsum[wid >> 10]);
    int n     = __builtin_amdgcn_readfirstlane(deg[wid]);
    float acc0 = 0.f, acc1 = 0.f, acc2 = 0.f, acc3 = 0.f;

    const uint_t* utj = utab + 2 * lane;
#if USE_FP8
    const uint_t* xqj = xq + lane;         // word = pairs 2l, 2l+1

#define EDGE_DO(CT, NM) do {                                         \
        int c_ = (int)((CT) & 0xFFFFu);                              \
        int t_ = (int)((CT) >> 16);                                  \
        uint_t xw_ = xqj[(size_t)c_ * 64];                           \
        uint2 uw_ = *(const uint2*)(utj + (size_t)t_ * HD);          \
        float nf_ = __uint_as_float(NM);                             \
        f32x2 p0_ = __builtin_amdgcn_cvt_pk_f32_fp8((int)xw_, false);\
        f32x2 p1_ = __builtin_amdgcn_cvt_pk_f32_fp8((int)xw_, true); \
        h2 cs0_ = bch2(uw_.x), cs1_ = bch2(uw_.y);                   \
        float c0_ = (float)cs0_[0], s0_ = (float)cs0_[1];            \
        float c1_ = (float)cs1_[0], s1_ = (float)cs1_[1];            \
        float rn0_ = nf_ * p0_[0], in0_ = nf_ * p0_[1];              \
        float rn1_ = nf_ * p1_[0], in1_ = nf_ * p1_[1];              \
        acc0 = fmaf(rn0_, c0_, fmaf(in0_, s0_, acc0));               \
        acc2 = fmaf(rn0_, s0_, fmaf(-in0_, c0_, acc2));              \
        acc1 = fmaf(rn1_, c1_, fmaf(in1_, s1_, acc1));               \
        acc3 = fmaf(rn1_, s1_, fmaf(-in1_, c1_, acc3));              \
    } while (0)
#else
    const uint_t* xcj = xc + 2 * lane;     // pairs j=2l, 2l+1

#define EDGE_DO(CT, NM) do {                                 \
        int c_ = (int)((CT) & 0xFFFFu);                      \
        int t_ = (int)((CT) >> 16);                          \
        uint2 xw_ = *(const uint2*)(xcj + (size_t)c_ * HD);  \
        uint2 uw_ = *(const uint2*)(utj + (size_t)t_ * HD);  \
        float nf_ = __uint_as_float(NM);                     \
        h2 nm2_; nm2_[0] = (_Float16)nf_; nm2_[1] = nm2_[0]; \
        h2 a0_ = bch2(xw_.x) * nm2_;                         \
        h2 a1_ = bch2(xw_.y) * nm2_;                         \
        uint_t sn0_ = ((uw_.x << 16) | (uw_.x >> 16)) ^ 0x80000000u; \
        uint_t sn1_ = ((uw_.y << 16) | (uw_.y >> 16)) ^ 0x80000000u; \
        acc0 = FDOT2(a0_, bch2(uw_.x), acc0);                \
        acc2 = FDOT2(a0_, bch2(sn0_), acc2);                 \
        acc1 = FDOT2(a1_, bch2(uw_.y), acc1);                \
        acc3 = FDOT2(a1_, bch2(sn1_), acc3);                 \
    } while (0)
#endif

    int i = 0;
    for (; i + 3 < n; i += 4) {
        uint2 e0 = ent[start + i];
        uint2 e1 = ent[start + i + 1];
        uint2 e2 = ent[start + i + 2];
        uint2 e3 = ent[start + i + 3];
        EDGE_DO(e0.x, e0.y);
        EDGE_DO(e1.x, e1.y);
        EDGE_DO(e2.x, e2.y);
        EDGE_DO(e3.x, e3.y);
    }
    for (; i < n; ++i) {
        uint2 e0 = ent[start + i];
        EDGE_DO(e0.x, e0.y);
    }
#undef EDGE_DO

    uint_t* Ar = (uint_t*)(A + (size_t)(dir * MPAD + row) * DD);
    Ar[lane]      = pkh2(acc0, acc1);   // elems 2l, 2l+1
    Ar[64 + lane] = pkh2(acc2, acc3);   // elems 128+2l, 128+2l+1
}

// ---------------- MFMA GEMM: BM=128, BN=128, BK=32, counted-vmcnt dbuf -----
// grid (391, 2) = 782 blocks (~3/CU), 4 waves (2Mx2N), 64x64 out per wave.
// out = [Ain|Aout|xc](M x 768) @ Wt^T   (1/3 pre-folded into Wt)
// Packed LDS rows (128B): A row R holds {m=R, m=R+64} x 32k; B row R holds
// {n=R, n=R+64} x 32k. 8 16B-slots/row, XOR-8 swizzled via pre-swizzled
// global source (linear LDS dest, rule-21 correct).
// Pipeline (T4): STAGE(next) then s_waitcnt vmcnt(4) — waits only for the
// PREVIOUS tile's 4 loads; the new 4 stay in flight across MFMA + barrier.
__global__ __launch_bounds__(256) void k_gemm(const ushort_t* __restrict__ Ain,
                                              const ushort_t* __restrict__ Aout,
                                              const ushort_t* __restrict__ xcf,
                                              const ushort_t* __restrict__ Wt,
                                              float* __restrict__ out) {
    __shared__ ushort_t Al[2][64 * 64];    // 8 KB per buf
    __shared__ ushort_t Bl[2][64 * 64];    // 8 KB per buf
    int tid = threadIdx.x;
    int m0 = blockIdx.x * 128;
    int n0 = blockIdx.y * 128;
    int lane = tid & 63, wv = tid >> 6;          // 4 waves: 2(M) x 2(N)
    int wrow = (wv >> 1) * 64, wcol = (wv & 1) * 64;
    int r = lane & 15, h = lane >> 4;            // h = k-octet 0..3

    f32x4 zero = {0.f, 0.f, 0.f, 0.f};
    f32x4 acc[4][4];
#pragma unroll
    for (int i = 0; i < 4; ++i)
#pragma unroll
        for (int j = 0; j < 4; ++j) acc[i][j] = zero;

#define STAGE(BUF, T) do {                                                     \
        int k0_ = (T) * 32;                                                    \
        const ushort_t* baseA_ = (k0_ < 256) ? Ain                             \
                                : ((k0_ < 512) ? Aout : xcf);                  \
        int kk0_ = k0_ & 255;                                                  \
        _Pragma("unroll")                                                      \
        for (int ss_ = 0; ss_ < 2; ++ss_) {  /* A: 512 slots, 2 per thread */  \
            int s_ = tid + ss_ * 256;                                          \
            int R_ = s_ >> 3, sl_ = s_ & 7, lsl_ = sl_ ^ (R_ & 7);             \
            int m_ = R_ + ((lsl_ >> 2) << 6), k8_ = (lsl_ & 3) << 3;           \
            GLOAD_LDS16(baseA_ + (size_t)(m0 + m_) * DD + kk0_ + k8_,          \
                        &Al[BUF][s_ * 8]);                                     \
        }                                                                      \
        _Pragma("unroll")                                                      \
        for (int ss_ = 0; ss_ < 2; ++ss_) {  /* B: 512 slots, 2 per thread */  \
            int s_ = tid + ss_ * 256;                                          \
            int R_ = s_ >> 3, sl_ = s_ & 7, lsl_ = sl_ ^ (R_ & 7);             \
            int n_ = n0 + R_ + ((lsl_ >> 2) << 6), k8_ = (lsl_ & 3) << 3;      \
            GLOAD_LDS16(Wt + (size_t)n_ * 768 + k0_ + k8_, &Bl[BUF][s_ * 8]);  \
        }                                                                      \
    } while (0)

    STAGE(0, 0);

    for (int t = 0; t < 24; ++t) {
        int cur = t & 1;
        if (t < 23) {
            STAGE(cur ^ 1, t + 1);   // 4 loads/thread into next buffer
            asm volatile("s_waitcnt vmcnt(4)" ::: "memory");  // prev tile landed
        } else {
            asm volatile("s_waitcnt vmcnt(0)" ::: "memory");
        }
        __builtin_amdgcn_s_barrier();            // all waves: cur buffer ready
        __builtin_amdgcn_sched_barrier(0);       // pin ds_reads after barrier
        h8 a[4], b[4];
#pragma unroll
        for (int i = 0; i < 4; ++i) {
            int mm = wrow + i * 16 + r;            // 0..127
            int R = mm & 63, half = mm >> 6;
            int sl = (half * 4 + h) ^ (R & 7);
            a[i] = *(const h8*)&Al[cur][R * 64 + sl * 8];
        }
#pragma unroll
        for (int j = 0; j < 4; ++j) {
            int nn = wcol + j * 16 + r;            // 0..127
            int R = nn & 63, half = nn >> 6;
            int sl = (half * 4 + h) ^ (R & 7);
            b[j] = *(const h8*)&Bl[cur][R * 64 + sl * 8];
        }
#pragma unroll
        for (int i = 0; i < 4; ++i)
#pragma unroll
            for (int j = 0; j < 4; ++j)
                acc[i][j] = __builtin_amdgcn_mfma_f32_16x16x32_f16(a[i], b[j], acc[i][j], 0, 0, 0);
        __builtin_amdgcn_s_barrier();  // reads of cur done before next re-stage
    }
#undef STAGE

    // C/D: col = lane&15, row = (lane>>4)*4 + reg (dtype-independent)
    int cn = lane & 15, rq = lane >> 4;
#pragma unroll
    for (int i = 0; i < 4; ++i)
#pragma unroll
        for (int j = 0; j < 4; ++j)
#pragma unroll
            for (int q = 0; q < 4; ++q) {
                int m = m0 + wrow + i * 16 + rq * 4 + q;
                if (m < N_ENT) {
                    int n = n0 + wcol + j * 16 + cn;
                    out[(size_t)m * DD + n] = acc[i][j][q];
                }
            }
}

extern "C" void kernel_launch(void* const* d_in, const int* in_sizes, int n_in,
                              void* d_out, int out_size, void* d_ws, size_t ws_size,
                              hipStream_t stream) {
    const float* x        = (const float*)d_in[0];
    const int*   ei       = (const int*)d_in[1];
    const int*   et       = (const int*)d_in[2];
    const float* rel      = (const float*)d_in[3];
    const float* w_loop   = (const float*)d_in[4];
    const float* w_in     = (const float*)d_in[5];
    const float* w_out    = (const float*)d_in[6];
    const float* w_rel    = (const float*)d_in[7];
    const float* loop_rel = (const float*)d_in[8];

    char* w = (char*)d_ws;
    ushort_t* A    = (ushort_t*)w;  w += (size_t)2 * MPAD * DD * 2;   // f16 [2][MPAD][DD]
    uint_t* xc     = (uint_t*)w;    w += (size_t)N_ENT * HD * 4;      // f16 packed pairs
    uint_t* xq     = (uint_t*)w;    w += (size_t)N_ENT * 64 * 4;      // fp8 packed pairs
    ushort_t* Wt   = (ushort_t*)w;  w += 256 * 768 * 2;
    uint_t* utab   = (uint_t*)w;    w += (size_t)N_RELS * HD * 4;
    int* deg_i     = (int*)w;       w += NK * 4;
    int* cnt       = (int*)w;       w += NK * 4;
    int* off       = (int*)w;       w += NK * 4;
    int* bsum      = (int*)w;       w += 128 * 4;
    float* dinv    = (float*)w;     w += NK * 4;
    uint2* ent     = (uint2*)w;     w += (size_t)ETOT * 8 + 64;       // +64B s_load pad
    ushort_t* Aout = A + (size_t)MPAD * DD;

    float* out     = (float*)d_out;
    float* rel_out = out + (size_t)N_ENT * DD;

    // zero deg_i + cnt (adjacent)
    hipMemsetAsync(deg_i, 0, (size_t)2 * NK * 4, stream);

    k_prepx <<<1600, 256, 0, stream>>>(x, xc, xq);
    k_preps <<<1757, 256, 0, stream>>>(rel, w_in, w_out, w_loop, loop_rel,
                                       w_rel, ei, utab, Wt, rel_out, deg_i);
    k_scan1 <<<NBLK, 256, 0, stream>>>(deg_i, off, bsum, dinv);
    k_scan2 <<<1, 128, 0, stream>>>(bsum);
    k_bucket<<<(ETOT + 255) / 256, 256, 0, stream>>>(ei, et, off, bsum, dinv, cnt, ent);
    k_gather<<<(NK + 3) / 4, 256, 0, stream>>>(ent, off, bsum, deg_i, xq, xc, utab, A);

    dim3 gg(MPAD / 128, 2);
    k_gemm  <<<gg, 256, 0, stream>>>(A, Aout, (const ushort_t*)xc, Wt, out);
}

// Round 20
// 156.475 us; speedup vs baseline: 1.0409x; 1.0409x over previous
//
#include <hip/hip_runtime.h>

#define N_ENT 50000
#define MPAD  50048            // 391*128, padded rows for GEMM staging
#define N_RELS 500
#define DD 256
#define HD 128
#define EPD 250000
#define ETOT 500000
#define NK (2 * N_ENT)         // (dir,row) keys
#define NBLK 98                // ceil(NK/1024)
#define REL_SCALE 2.0943951023931953f  // pi / 1.5

typedef unsigned short ushort_t;
typedef unsigned int uint_t;
typedef __attribute__((ext_vector_type(2))) _Float16 h2;
typedef __attribute__((ext_vector_type(8))) _Float16 h8;
typedef __attribute__((ext_vector_type(2))) float f32x2;
typedef __attribute__((ext_vector_type(4))) float f32x4;
typedef __attribute__((ext_vector_type(4))) uint_t u32x4;

#if __has_builtin(__builtin_amdgcn_cvt_pk_f32_fp8) && __has_builtin(__builtin_amdgcn_cvt_pk_fp8_f32)
#define USE_FP8 1
#else
#define USE_FP8 0
#endif

__device__ inline uint_t pkh2(float a, float b) {
    union { _Float16 h[2]; uint_t u; } v;
    v.h[0] = (_Float16)a; v.h[1] = (_Float16)b; return v.u;
}
__device__ inline h2 bch2(uint_t w) {
    union { uint_t u; h2 h; } v; v.u = w; return v.h;
}

#if __has_builtin(__builtin_amdgcn_fdot2)
#define FDOT2(a, b, c) __builtin_amdgcn_fdot2((a), (b), (c), false)
#else
__device__ inline float FDOT2(h2 a, h2 b, float c) {
    return c + (float)a[0] * (float)b[0] + (float)a[1] * (float)b[1];
}
#endif

#define GLOAD_LDS16(g, l) __builtin_amdgcn_global_load_lds( \
    (const __attribute__((address_space(1))) unsigned int*)(g), \
    (__attribute__((address_space(3))) unsigned int*)(l), 16, 0, 0)

// ---------------- per-block exclusive scan + dinv (98 blocks) --------------
__global__ __launch_bounds__(256) void k_scan1(const int* __restrict__ deg,
                                               int* __restrict__ off,
                                               int* __restrict__ bsum,
                                               float* __restrict__ dinv) {
    __shared__ int wsum[4];
    int b = blockIdx.x, t = threadIdx.x;
    int base = b * 1024 + t * 4;
    int v[4];
#pragma unroll
    for (int i = 0; i < 4; ++i) v[i] = (base + i < NK) ? deg[base + i] : 0;
    int tsum = v[0] + v[1] + v[2] + v[3];
    int lane = t & 63, w = t >> 6;
    int incl = tsum;
    for (int d = 1; d < 64; d <<= 1) {
        int y = __shfl_up(incl, d);
        if (lane >= d) incl += y;
    }
    if (lane == 63) wsum[w] = incl;
    __syncthreads();
    int woff = 0;
    for (int k = 0; k < w; ++k) woff += wsum[k];
    int run = woff + incl - tsum;
#pragma unroll
    for (int i = 0; i < 4; ++i) {
        if (base + i < NK) {
            off[base + i] = run;
            dinv[base + i] = (v[i] > 0) ? rsqrtf((float)v[i]) : 0.0f;
        }
        run += v[i];
    }
    if (t == 255) bsum[b] = woff + incl;   // block total
}

__global__ void k_scan2(int* __restrict__ bsum) {
    __shared__ int s[NBLK];
    int t = threadIdx.x;
    if (t < NBLK) s[t] = bsum[t];
    __syncthreads();
    if (t == 0) {
        int c = 0;
        for (int i = 0; i < NBLK; ++i) { int x = s[i]; s[i] = c; c += x; }
    }
    __syncthreads();
    if (t < NBLK) bsum[t] = s[t];
}

// ---------------- bucket edges: 8B entry {col|t<<16, f32 norm} -------------
__global__ __launch_bounds__(256) void k_bucket(const int* __restrict__ ei,
                                                const int* __restrict__ et,
                                                const int* __restrict__ off,
                                                const int* __restrict__ bsum,
                                                const float* __restrict__ dinv,
                                                int* __restrict__ cnt,
                                                uint2* __restrict__ ent) {
    int e = blockIdx.x * 256 + threadIdx.x;
    if (e >= ETOT) return;
    int dir = (e >= EPD);
    int key = dir * N_ENT + ei[e];
    int pos = off[key] + bsum[key >> 10] + atomicAdd(cnt + key, 1);
    int col = ei[ETOT + e];
    int t   = et[e];
    float nm = dinv[key] * dinv[dir * N_ENT + col];
    ent[pos] = make_uint2((uint_t)col | ((uint_t)t << 16), __float_as_uint(nm));
}

// ---------------- prepx: xc + xq, 4 chunks/thread for MLP (1600 blocks) ----
// chunk ci: col = ci>>5, pairs q=(ci&31)*4 .. +3
// xc[col*128 + p] = pack_f16(x[col][p], x[col][p+128])      (for GEMM)
// xq[col*64 + w]  = fp8 {re(2w), im(2w), re(2w+1), im(2w+1)} (for gather)
// All 8 loads issued before any store -> 8 HBM transactions in flight/thread.
__global__ __launch_bounds__(256) void k_prepx(const float* __restrict__ x,
                                               uint_t* __restrict__ xc,
                                               uint_t* __restrict__ xq) {
    int t0 = blockIdx.x * 256 + threadIdx.x;   // 0..409599
    f32x4 re0, re1, re2, re3, im0, im1, im2, im3;
    int c0, c1, c2, c3;
#define LOADU(U, RE, IM, CI) do {                                   \
        int c_ = t0 + (U) * 409600;                                 \
        CI = (c_ < 1600000) ? c_ : 1599999;                         \
        int col_ = CI >> 5, q_ = (CI & 31) << 2;                    \
        const f32x4* xr_ = (const f32x4*)(x + (size_t)col_ * DD);   \
        RE = xr_[q_ >> 2];                                          \
        IM = xr_[(q_ + HD) >> 2];                                   \
    } while (0)
    LOADU(0, re0, im0, c0);
    LOADU(1, re1, im1, c1);
    LOADU(2, re2, im2, c2);
    LOADU(3, re3, im3, c3);
#undef LOADU
#define STOREU(RE, IM, CI) do {                                     \
        int col_ = CI >> 5, q_ = (CI & 31) << 2;                    \
        u32x4 o_;                                                   \
        o_.x = pkh2(RE.x, IM.x);                                    \
        o_.y = pkh2(RE.y, IM.y);                                    \
        o_.z = pkh2(RE.z, IM.z);                                    \
        o_.w = pkh2(RE.w, IM.w);                                    \
        *(u32x4*)(xc + (size_t)col_ * HD + q_) = o_;                \
        int w0_ = __builtin_amdgcn_cvt_pk_fp8_f32(RE.x, IM.x, 0, 0);\
        w0_     = __builtin_amdgcn_cvt_pk_fp8_f32(RE.y, IM.y, w0_, 1);\
        int w1_ = __builtin_amdgcn_cvt_pk_fp8_f32(RE.z, IM.z, 0, 0);\
        w1_     = __builtin_amdgcn_cvt_pk_fp8_f32(RE.w, IM.w, w1_, 1);\
        *(uint2*)(xq + (size_t)col_ * 64 + (q_ >> 1)) =             \
            make_uint2((uint_t)w0_, (uint_t)w1_);                   \
    } while (0)
#if USE_FP8
    STOREU(re0, im0, c0);
    STOREU(re1, im1, c1);
    STOREU(re2, im2, c2);
    STOREU(re3, im3, c3);
#else
    // f16-only fallback (xq unused; gather falls back to xc path)
#define STOREH(RE, IM, CI) do {                                     \
        int col_ = CI >> 5, q_ = (CI & 31) << 2;                    \
        u32x4 o_;                                                   \
        o_.x = pkh2(RE.x, IM.x);                                    \
        o_.y = pkh2(RE.y, IM.y);                                    \
        o_.z = pkh2(RE.z, IM.z);                                    \
        o_.w = pkh2(RE.w, IM.w);                                    \
        *(u32x4*)(xc + (size_t)col_ * HD + q_) = o_;                \
    } while (0)
    STOREH(re0, im0, c0);
    STOREH(re1, im1, c1);
    STOREH(re2, im2, c2);
    STOREH(re3, im3, c3);
#undef STOREH
#endif
#undef STOREU
}

// ---- preps: utab (250) + Wt/3 (768) + relout (250) + deg4 (489) = 1757 ----
__global__ __launch_bounds__(256) void k_preps(const float* __restrict__ rel,
                                               const float* __restrict__ w_in,
                                               const float* __restrict__ w_out,
                                               const float* __restrict__ w_loop,
                                               const float* __restrict__ loop_rel,
                                               const float* __restrict__ w_rel,
                                               const int* __restrict__ ei,
                                               uint_t* __restrict__ utab,
                                               ushort_t* __restrict__ Wt,
                                               float* __restrict__ rel_out,
                                               int* __restrict__ deg) {
    int b = blockIdx.x, tid = threadIdx.x;
    if (b < 250) {                         // utab (cs only)
        int idx = b * 256 + tid;           // < 64000 = 500*128
        float s, c;
        __sincosf(rel[idx] * REL_SCALE, &s, &c);
        utab[idx] = pkh2(c, s);
    } else if (b < 1018) {                 // Wt[256n][768k] f16, /3 folded
        int idx = (b - 250) * 256 + tid;   // < 196608
        int n = idx / 768, k = idx - n * 768;
        float v;
        if (k < 256) {
            v = w_in[k * 256 + n];
        } else if (k < 512) {
            v = w_out[(k - 256) * 256 + n];
        } else {
            // third A-block is xc (interleaved): kk=2p -> x[p], kk=2p+1 -> x[p+128]
            int kk = k - 512;
            int jj = kk >> 1;
            float s, c;
            __sincosf(loop_rel[jj] * REL_SCALE, &s, &c);
            float w0 = w_loop[jj * 256 + n];
            float w1 = w_loop[(jj + HD) * 256 + n];
            v = ((kk & 1) == 0) ? (c * w0 + s * w1) : (s * w0 - c * w1);
        }
        union { _Float16 h; ushort_t u; } cv; cv.h = (_Float16)(v * (1.0f / 3.0f));
        Wt[idx] = cv.u;
    } else if (b < 1268) {                 // rel_out = rel_embed @ w_rel
        int idx = (b - 1018) * 256 + tid;  // < 64000
        int i = idx >> 7, c = idx & 127;
        float acc = 0.0f;
        for (int k = 0; k < HD; ++k) acc += rel[i * HD + k] * w_rel[k * HD + c];
        rel_out[idx] = acc;
    } else {                               // degree histogram, 4 edges/thread
        int e4 = ((b - 1268) * 256 + tid) * 4;   // < 500000
        if (e4 < ETOT) {
            int4 r4 = *(const int4*)(ei + e4);
#pragma unroll
            for (int q = 0; q < 4; ++q) {
                int e = e4 + q;
                int rv = (q == 0) ? r4.x : (q == 1) ? r4.y : (q == 2) ? r4.z : r4.w;
                if (e < ETOT) {
                    int key = (e >= EPD ? N_ENT : 0) + rv;
                    atomicAdd(deg + key, 1);
                }
            }
        }
    }
}

// ---------------- gather: one wave per (dir,row), 2 pairs per lane ---------
//   out_lo[j] = (re,im).(c,s)   -> A elem j
//   out_hi[j] = (re,im).(s,-c)  -> A elem j+128
// fp8 path: 4B/lane x-row load, v_cvt_pk_f32_fp8 decode, f32 FMA math.
__global__ __launch_bounds__(256) void k_gather(const uint2* __restrict__ ent,
                                                const int* __restrict__ off,
                                                const int* __restrict__ bsum,
                                                const int* __restrict__ deg,
                                                const uint_t* __restrict__ xq,
                                                const uint_t* __restrict__ xc,
                                                const uint_t* __restrict__ utab,
                                                ushort_t* __restrict__ A) {
    int wid  = (blockIdx.x * 256 + threadIdx.x) >> 6;
    int lane = threadIdx.x & 63;
    if (wid >= NK) return;
    int dir = (wid >= N_ENT);
    int row = wid - dir * N_ENT;
    int start = __builtin_amdgcn_readfirstlane(off[wid] + bsum[wid >> 10]);
    int n     = __builtin_amdgcn_readfirstlane(deg[wid]);
    float acc0 = 0.f, acc1 = 0.f, acc2 = 0.f, acc3 = 0.f;

    const uint_t* utj = utab + 2 * lane;
#if USE_FP8
    const uint_t* xqj = xq + lane;         // word = pairs 2l, 2l+1

#define EDGE_DO(CT, NM) do {                                         \
        int c_ = (int)((CT) & 0xFFFFu);                              \
        int t_ = (int)((CT) >> 16);                                  \
        uint_t xw_ = xqj[(size_t)c_ * 64];                           \
        uint2 uw_ = *(const uint2*)(utj + (size_t)t_ * HD);          \
        float nf_ = __uint_as_float(NM);                             \
        f32x2 p0_ = __builtin_amdgcn_cvt_pk_f32_fp8((int)xw_, false);\
        f32x2 p1_ = __builtin_amdgcn_cvt_pk_f32_fp8((int)xw_, true); \
        h2 cs0_ = bch2(uw_.x), cs1_ = bch2(uw_.y);                   \
        float c0_ = (float)cs0_[0], s0_ = (float)cs0_[1];            \
        float c1_ = (float)cs1_[0], s1_ = (float)cs1_[1];            \
        float rn0_ = nf_ * p0_[0], in0_ = nf_ * p0_[1];              \
        float rn1_ = nf_ * p1_[0], in1_ = nf_ * p1_[1];              \
        acc0 = fmaf(rn0_, c0_, fmaf(in0_, s0_, acc0));               \
        acc2 = fmaf(rn0_, s0_, fmaf(-in0_, c0_, acc2));              \
        acc1 = fmaf(rn1_, c1_, fmaf(in1_, s1_, acc1));               \
        acc3 = fmaf(rn1_, s1_, fmaf(-in1_, c1_, acc3));              \
    } while (0)
#else
    const uint_t* xcj = xc + 2 * lane;     // pairs j=2l, 2l+1

#define EDGE_DO(CT, NM) do {                                 \
        int c_ = (int)((CT) & 0xFFFFu);                      \
        int t_ = (int)((CT) >> 16);                          \
        uint2 xw_ = *(const uint2*)(xcj + (size_t)c_ * HD);  \
        uint2 uw_ = *(const uint2*)(utj + (size_t)t_ * HD);  \
        float nf_ = __uint_as_float(NM);                     \
        h2 nm2_; nm2_[0] = (_Float16)nf_; nm2_[1] = nm2_[0]; \
        h2 a0_ = bch2(xw_.x) * nm2_;                         \
        h2 a1_ = bch2(xw_.y) * nm2_;                         \
        uint_t sn0_ = ((uw_.x << 16) | (uw_.x >> 16)) ^ 0x80000000u; \
        uint_t sn1_ = ((uw_.y << 16) | (uw_.y >> 16)) ^ 0x80000000u; \
        acc0 = FDOT2(a0_, bch2(uw_.x), acc0);                \
        acc2 = FDOT2(a0_, bch2(sn0_), acc2);                 \
        acc1 = FDOT2(a1_, bch2(uw_.y), acc1);                \
        acc3 = FDOT2(a1_, bch2(sn1_), acc3);                 \
    } while (0)
#endif

    int i = 0;
    for (; i + 3 < n; i += 4) {
        uint2 e0 = ent[start + i];
        uint2 e1 = ent[start + i + 1];
        uint2 e2 = ent[start + i + 2];
        uint2 e3 = ent[start + i + 3];
        EDGE_DO(e0.x, e0.y);
        EDGE_DO(e1.x, e1.y);
        EDGE_DO(e2.x, e2.y);
        EDGE_DO(e3.x, e3.y);
    }
    for (; i < n; ++i) {
        uint2 e0 = ent[start + i];
        EDGE_DO(e0.x, e0.y);
    }
#undef EDGE_DO

    uint_t* Ar = (uint_t*)(A + (size_t)(dir * MPAD + row) * DD);
    Ar[lane]      = pkh2(acc0, acc1);   // elems 2l, 2l+1
    Ar[64 + lane] = pkh2(acc2, acc3);   // elems 128+2l, 128+2l+1
}

// ---------------- MFMA GEMM: BM=128, BN=128, BK=32, 8 waves, dbuf ----------
// grid (2, 391): x = N-half runs FASTEST in dispatch order, so both N-halves
// of an M-tile read the same A rows back-to-back -> L2/L3 hot (r19 fix).
// 512 thr = 8 waves (2M x 4N), 64x32 out per wave, 8 MFMA/iter.
// out = [Ain|Aout|xc](M x 768) @ Wt^T   (1/3 pre-folded into Wt)
// Packed LDS rows (128B): A row R holds {m=R, m=R+64} x 32k; B row R holds
// {n=R, n=R+64} x 32k. 8 16B-slots/row, XOR-8 swizzled via pre-swizzled
// global source (linear LDS dest, rule-21 correct).
// Pipeline (T4): STAGE(next) then s_waitcnt vmcnt(2) — waits only for the
// PREVIOUS tile's 2 loads; the new 2 stay in flight across MFMA + barrier.
__global__ __launch_bounds__(512) void k_gemm(const ushort_t* __restrict__ Ain,
                                              const ushort_t* __restrict__ Aout,
                                              const ushort_t* __restrict__ xcf,
                                              const ushort_t* __restrict__ Wt,
                                              float* __restrict__ out) {
    __shared__ ushort_t Al[2][64 * 64];    // 8 KB per buf
    __shared__ ushort_t Bl[2][64 * 64];    // 8 KB per buf
    int tid = threadIdx.x;
    int n0 = blockIdx.x * 128;             // x fastest: N-half
    int m0 = blockIdx.y * 128;
    int lane = tid & 63, wv = tid >> 6;          // 8 waves: 2(M) x 4(N)
    int wrow = (wv >> 2) * 64, wcol = (wv & 3) * 32;
    int r = lane & 15, h = lane >> 4;            // h = k-octet 0..3

    f32x4 zero = {0.f, 0.f, 0.f, 0.f};
    f32x4 acc[4][2];
#pragma unroll
    for (int i = 0; i < 4; ++i)
#pragma unroll
        for (int j = 0; j < 2; ++j) acc[i][j] = zero;

#define STAGE(BUF, T) do {                                                     \
        int k0_ = (T) * 32;                                                    \
        const ushort_t* baseA_ = (k0_ < 256) ? Ain                             \
                                : ((k0_ < 512) ? Aout : xcf);                  \
        int kk0_ = k0_ & 255;                                                  \
        {   /* A: 512 slots, 1 per thread */                                   \
            int R_ = tid >> 3, sl_ = tid & 7, lsl_ = sl_ ^ (R_ & 7);           \
            int m_ = R_ + ((lsl_ >> 2) << 6), k8_ = (lsl_ & 3) << 3;           \
            GLOAD_LDS16(baseA_ + (size_t)(m0 + m_) * DD + kk0_ + k8_,          \
                        &Al[BUF][tid * 8]);                                    \
        }                                                                      \
        {   /* B: 512 slots, 1 per thread */                                   \
            int R_ = tid >> 3, sl_ = tid & 7, lsl_ = sl_ ^ (R_ & 7);           \
            int n_ = n0 + R_ + ((lsl_ >> 2) << 6), k8_ = (lsl_ & 3) << 3;      \
            GLOAD_LDS16(Wt + (size_t)n_ * 768 + k0_ + k8_, &Bl[BUF][tid * 8]); \
        }                                                                      \
    } while (0)

    STAGE(0, 0);

    for (int t = 0; t < 24; ++t) {
        int cur = t & 1;
        if (t < 23) {
            STAGE(cur ^ 1, t + 1);   // 2 loads/thread into next buffer
            asm volatile("s_waitcnt vmcnt(2)" ::: "memory");  // prev tile landed
        } else {
            asm volatile("s_waitcnt vmcnt(0)" ::: "memory");
        }
        __builtin_amdgcn_s_barrier();            // all waves: cur buffer ready
        __builtin_amdgcn_sched_barrier(0);       // pin ds_reads after barrier
        h8 a[4], b[2];
#pragma unroll
        for (int i = 0; i < 4; ++i) {
            int mm = wrow + i * 16 + r;            // 0..127
            int R = mm & 63, half = mm >> 6;
            int sl = (half * 4 + h) ^ (R & 7);
            a[i] = *(const h8*)&Al[cur][R * 64 + sl * 8];
        }
#pragma unroll
        for (int j = 0; j < 2; ++j) {
            int nn = wcol + j * 16 + r;            // 0..127
            int R = nn & 63, half = nn >> 6;
            int sl = (half * 4 + h) ^ (R & 7);
            b[j] = *(const h8*)&Bl[cur][R * 64 + sl * 8];
        }
#pragma unroll
        for (int i = 0; i < 4; ++i)
#pragma unroll
            for (int j = 0; j < 2; ++j)
                acc[i][j] = __builtin_amdgcn_mfma_f32_16x16x32_f16(a[i], b[j], acc[i][j], 0, 0, 0);
        __builtin_amdgcn_s_barrier();  // reads of cur done before next re-stage
    }
#undef STAGE

    // C/D: col = lane&15, row = (lane>>4)*4 + reg (dtype-independent)
    int cn = lane & 15, rq = lane >> 4;
#pragma unroll
    for (int i = 0; i < 4; ++i)
#pragma unroll
        for (int j = 0; j < 2; ++j)
#pragma unroll
            for (int q = 0; q < 4; ++q) {
                int m = m0 + wrow + i * 16 + rq * 4 + q;
                if (m < N_ENT) {
                    int n = n0 + wcol + j * 16 + cn;
                    out[(size_t)m * DD + n] = acc[i][j][q];
                }
            }
}

extern "C" void kernel_launch(void* const* d_in, const int* in_sizes, int n_in,
                              void* d_out, int out_size, void* d_ws, size_t ws_size,
                              hipStream_t stream) {
    const float* x        = (const float*)d_in[0];
    const int*   ei       = (const int*)d_in[1];
    const int*   et       = (const int*)d_in[2];
    const float* rel      = (const float*)d_in[3];
    const float* w_loop   = (const float*)d_in[4];
    const float* w_in     = (const float*)d_in[5];
    const float* w_out    = (const float*)d_in[6];
    const float* w_rel    = (const float*)d_in[7];
    const float* loop_rel = (const float*)d_in[8];

    char* w = (char*)d_ws;
    ushort_t* A    = (ushort_t*)w;  w += (size_t)2 * MPAD * DD * 2;   // f16 [2][MPAD][DD]
    uint_t* xc     = (uint_t*)w;    w += (size_t)N_ENT * HD * 4;      // f16 packed pairs
    uint_t* xq     = (uint_t*)w;    w += (size_t)N_ENT * 64 * 4;      // fp8 packed pairs
    ushort_t* Wt   = (ushort_t*)w;  w += 256 * 768 * 2;
    uint_t* utab   = (uint_t*)w;    w += (size_t)N_RELS * HD * 4;
    int* deg_i     = (int*)w;       w += NK * 4;
    int* cnt       = (int*)w;       w += NK * 4;
    int* off       = (int*)w;       w += NK * 4;
    int* bsum      = (int*)w;       w += 128 * 4;
    float* dinv    = (float*)w;     w += NK * 4;
    uint2* ent     = (uint2*)w;     w += (size_t)ETOT * 8 + 64;       // +64B s_load pad
    ushort_t* Aout = A + (size_t)MPAD * DD;

    float* out     = (float*)d_out;
    float* rel_out = out + (size_t)N_ENT * DD;

    // zero deg_i + cnt (adjacent)
    hipMemsetAsync(deg_i, 0, (size_t)2 * NK * 4, stream);

    k_prepx <<<1600, 256, 0, stream>>>(x, xc, xq);
    k_preps <<<1757, 256, 0, stream>>>(rel, w_in, w_out, w_loop, loop_rel,
                                       w_rel, ei, utab, Wt, rel_out, deg_i);
    k_scan1 <<<NBLK, 256, 0, stream>>>(deg_i, off, bsum, dinv);
    k_scan2 <<<1, 128, 0, stream>>>(bsum);
    k_bucket<<<(ETOT + 255) / 256, 256, 0, stream>>>(ei, et, off, bsum, dinv, cnt, ent);
    k_gather<<<(NK + 3) / 4, 256, 0, stream>>>(ent, off, bsum, deg_i, xq, xc, utab, A);

    dim3 gg(2, MPAD / 128);
    k_gemm  <<<gg, 512, 0, stream>>>(A, Aout, (const ushort_t*)xc, Wt, out);
}

// Round 21
// 143.365 us; speedup vs baseline: 1.1361x; 1.0914x over previous
//
#include <hip/hip_runtime.h>

#define N_ENT 50000
#define MPAD  50048            // 391*128, padded rows for GEMM staging
#define N_RELS 500
#define DD 256
#define HD 128
#define EPD 250000
#define ETOT 500000
#define NK (2 * N_ENT)         // (dir,row) keys
#define NBLK 98                // ceil(NK/1024)
#define REL_SCALE 2.0943951023931953f  // pi / 1.5

typedef unsigned short ushort_t;
typedef unsigned int uint_t;
typedef __attribute__((ext_vector_type(2))) _Float16 h2;
typedef __attribute__((ext_vector_type(8))) _Float16 h8;
typedef __attribute__((ext_vector_type(2))) float f32x2;
typedef __attribute__((ext_vector_type(4))) float f32x4;
typedef __attribute__((ext_vector_type(4))) uint_t u32x4;

#if __has_builtin(__builtin_amdgcn_cvt_pk_f32_fp8) && __has_builtin(__builtin_amdgcn_cvt_pk_fp8_f32)
#define USE_FP8 1
#else
#define USE_FP8 0
#endif

__device__ inline uint_t pkh2(float a, float b) {
    union { _Float16 h[2]; uint_t u; } v;
    v.h[0] = (_Float16)a; v.h[1] = (_Float16)b; return v.u;
}
__device__ inline h2 bch2(uint_t w) {
    union { uint_t u; h2 h; } v; v.u = w; return v.h;
}

#if __has_builtin(__builtin_amdgcn_fdot2)
#define FDOT2(a, b, c) __builtin_amdgcn_fdot2((a), (b), (c), false)
#else
__device__ inline float FDOT2(h2 a, h2 b, float c) {
    return c + (float)a[0] * (float)b[0] + (float)a[1] * (float)b[1];
}
#endif

#define GLOAD_LDS16(g, l) __builtin_amdgcn_global_load_lds( \
    (const __attribute__((address_space(1))) unsigned int*)(g), \
    (__attribute__((address_space(3))) unsigned int*)(l), 16, 0, 0)

// ---------------- per-block exclusive scan + dinv (98 blocks) --------------
__global__ __launch_bounds__(256) void k_scan1(const int* __restrict__ deg,
                                               int* __restrict__ off,
                                               int* __restrict__ bsum,
                                               float* __restrict__ dinv) {
    __shared__ int wsum[4];
    int b = blockIdx.x, t = threadIdx.x;
    int base = b * 1024 + t * 4;
    int v[4];
#pragma unroll
    for (int i = 0; i < 4; ++i) v[i] = (base + i < NK) ? deg[base + i] : 0;
    int tsum = v[0] + v[1] + v[2] + v[3];
    int lane = t & 63, w = t >> 6;
    int incl = tsum;
    for (int d = 1; d < 64; d <<= 1) {
        int y = __shfl_up(incl, d);
        if (lane >= d) incl += y;
    }
    if (lane == 63) wsum[w] = incl;
    __syncthreads();
    int woff = 0;
    for (int k = 0; k < w; ++k) woff += wsum[k];
    int run = woff + incl - tsum;
#pragma unroll
    for (int i = 0; i < 4; ++i) {
        if (base + i < NK) {
            off[base + i] = run;
            dinv[base + i] = (v[i] > 0) ? rsqrtf((float)v[i]) : 0.0f;
        }
        run += v[i];
    }
    if (t == 255) bsum[b] = woff + incl;   // block total
}

__global__ void k_scan2(int* __restrict__ bsum) {
    __shared__ int s[NBLK];
    int t = threadIdx.x;
    if (t < NBLK) s[t] = bsum[t];
    __syncthreads();
    if (t == 0) {
        int c = 0;
        for (int i = 0; i < NBLK; ++i) { int x = s[i]; s[i] = c; c += x; }
    }
    __syncthreads();
    if (t < NBLK) bsum[t] = s[t];
}

// ---------------- bucket edges: 8B entry {col|t<<16, f32 norm} -------------
__global__ __launch_bounds__(256) void k_bucket(const int* __restrict__ ei,
                                                const int* __restrict__ et,
                                                const int* __restrict__ off,
                                                const int* __restrict__ bsum,
                                                const float* __restrict__ dinv,
                                                int* __restrict__ cnt,
                                                uint2* __restrict__ ent) {
    int e = blockIdx.x * 256 + threadIdx.x;
    if (e >= ETOT) return;
    int dir = (e >= EPD);
    int key = dir * N_ENT + ei[e];
    int pos = off[key] + bsum[key >> 10] + atomicAdd(cnt + key, 1);
    int col = ei[ETOT + e];
    int t   = et[e];
    float nm = dinv[key] * dinv[dir * N_ENT + col];
    ent[pos] = make_uint2((uint_t)col | ((uint_t)t << 16), __float_as_uint(nm));
}

// ---- prep: xcq MLP (1600) + utab (250) + Wt/3 (768) + relout (250) + deg4 -
// seg0 chunk ci: col = ci>>5, pairs q=(ci&31)*4 .. +3
// xc[col*128 + p] = pack_f16(x[col][p], x[col][p+128])      (for GEMM)
// xq[col*64 + w]  = fp8 {re(2w), im(2w), re(2w+1), im(2w+1)} (for gather)
__global__ __launch_bounds__(256) void k_prep(const float* __restrict__ x,
                                              const float* __restrict__ rel,
                                              const float* __restrict__ w_in,
                                              const float* __restrict__ w_out,
                                              const float* __restrict__ w_loop,
                                              const float* __restrict__ loop_rel,
                                              const float* __restrict__ w_rel,
                                              const int* __restrict__ ei,
                                              uint_t* __restrict__ xc,
                                              uint_t* __restrict__ xq,
                                              uint_t* __restrict__ utab,
                                              ushort_t* __restrict__ Wt,
                                              float* __restrict__ rel_out,
                                              int* __restrict__ deg) {
    int b = blockIdx.x, tid = threadIdx.x;
    if (b < 1600) {                        // xc/xq: 4 chunks/thread, MLP-batched
        int t0 = b * 256 + tid;            // 0..409599
        f32x4 re0, re1, re2, re3, im0, im1, im2, im3;
        int c0, c1, c2, c3;
#define LOADU(U, RE, IM, CI) do {                                   \
        int c_ = t0 + (U) * 409600;                                 \
        CI = (c_ < 1600000) ? c_ : 1599999;                         \
        int col_ = CI >> 5, q_ = (CI & 31) << 2;                    \
        const f32x4* xr_ = (const f32x4*)(x + (size_t)col_ * DD);   \
        RE = xr_[q_ >> 2];                                          \
        IM = xr_[(q_ + HD) >> 2];                                   \
    } while (0)
        LOADU(0, re0, im0, c0);
        LOADU(1, re1, im1, c1);
        LOADU(2, re2, im2, c2);
        LOADU(3, re3, im3, c3);
#undef LOADU
#if USE_FP8
#define STOREU(RE, IM, CI) do {                                     \
        int col_ = CI >> 5, q_ = (CI & 31) << 2;                    \
        u32x4 o_;                                                   \
        o_.x = pkh2(RE.x, IM.x);                                    \
        o_.y = pkh2(RE.y, IM.y);                                    \
        o_.z = pkh2(RE.z, IM.z);                                    \
        o_.w = pkh2(RE.w, IM.w);                                    \
        *(u32x4*)(xc + (size_t)col_ * HD + q_) = o_;                \
        int w0_ = __builtin_amdgcn_cvt_pk_fp8_f32(RE.x, IM.x, 0, 0);\
        w0_     = __builtin_amdgcn_cvt_pk_fp8_f32(RE.y, IM.y, w0_, 1);\
        int w1_ = __builtin_amdgcn_cvt_pk_fp8_f32(RE.z, IM.z, 0, 0);\
        w1_     = __builtin_amdgcn_cvt_pk_fp8_f32(RE.w, IM.w, w1_, 1);\
        *(uint2*)(xq + (size_t)col_ * 64 + (q_ >> 1)) =             \
            make_uint2((uint_t)w0_, (uint_t)w1_);                   \
    } while (0)
#else
#define STOREU(RE, IM, CI) do {                                     \
        int col_ = CI >> 5, q_ = (CI & 31) << 2;                    \
        u32x4 o_;                                                   \
        o_.x = pkh2(RE.x, IM.x);                                    \
        o_.y = pkh2(RE.y, IM.y);                                    \
        o_.z = pkh2(RE.z, IM.z);                                    \
        o_.w = pkh2(RE.w, IM.w);                                    \
        *(u32x4*)(xc + (size_t)col_ * HD + q_) = o_;                \
    } while (0)
#endif
        STOREU(re0, im0, c0);
        STOREU(re1, im1, c1);
        STOREU(re2, im2, c2);
        STOREU(re3, im3, c3);
#undef STOREU
    } else if (b < 1850) {                 // utab (cs only)
        int idx = (b - 1600) * 256 + tid;  // < 64000 = 500*128
        float s, c;
        __sincosf(rel[idx] * REL_SCALE, &s, &c);
        utab[idx] = pkh2(c, s);
    } else if (b < 2618) {                 // Wt[256n][768k] f16, /3 folded
        int idx = (b - 1850) * 256 + tid;  // < 196608
        int n = idx / 768, k = idx - n * 768;
        float v;
        if (k < 256) {
            v = w_in[k * 256 + n];
        } else if (k < 512) {
            v = w_out[(k - 256) * 256 + n];
        } else {
            // third A-block is xc (interleaved): kk=2p -> x[p], kk=2p+1 -> x[p+128]
            int kk = k - 512;
            int jj = kk >> 1;
            float s, c;
            __sincosf(loop_rel[jj] * REL_SCALE, &s, &c);
            float w0 = w_loop[jj * 256 + n];
            float w1 = w_loop[(jj + HD) * 256 + n];
            v = ((kk & 1) == 0) ? (c * w0 + s * w1) : (s * w0 - c * w1);
        }
        union { _Float16 h; ushort_t u; } cv; cv.h = (_Float16)(v * (1.0f / 3.0f));
        Wt[idx] = cv.u;
    } else if (b < 2868) {                 // rel_out = rel_embed @ w_rel
        int idx = (b - 2618) * 256 + tid;  // < 64000
        int i = idx >> 7, c = idx & 127;
        float acc = 0.0f;
        for (int k = 0; k < HD; ++k) acc += rel[i * HD + k] * w_rel[k * HD + c];
        rel_out[idx] = acc;
    } else {                               // degree histogram, 4 edges/thread
        int e4 = ((b - 2868) * 256 + tid) * 4;   // < 500000
        if (e4 < ETOT) {
            int4 r4 = *(const int4*)(ei + e4);
#pragma unroll
            for (int q = 0; q < 4; ++q) {
                int e = e4 + q;
                int rv = (q == 0) ? r4.x : (q == 1) ? r4.y : (q == 2) ? r4.z : r4.w;
                if (e < ETOT) {
                    int key = (e >= EPD ? N_ENT : 0) + rv;
                    atomicAdd(deg + key, 1);
                }
            }
        }
    }
}

// ---------------- gather: one wave per (dir,row), 2 pairs per lane ---------
//   out_lo[j] = (re,im).(c,s)   -> A elem j
//   out_hi[j] = (re,im).(s,-c)  -> A elem j+128
// fp8 path: 4B/lane x-row load, v_cvt_pk_f32_fp8 decode, f32 FMA math.
__global__ __launch_bounds__(256) void k_gather(const uint2* __restrict__ ent,
                                                const int* __restrict__ off,
                                                const int* __restrict__ bsum,
                                                const int* __restrict__ deg,
                                                const uint_t* __restrict__ xq,
                                                const uint_t* __restrict__ xc,
                                                const uint_t* __restrict__ utab,
                                                ushort_t* __restrict__ A) {
    int wid  = (blockIdx.x * 256 + threadIdx.x) >> 6;
    int lane = threadIdx.x & 63;
    if (wid >= NK) return;
    int dir = (wid >= N_ENT);
    int row = wid - dir * N_ENT;
    int start = __builtin_amdgcn_readfirstlane(off[wid] + bsum[wid >> 10]);
    int n     = __builtin_amdgcn_readfirstlane(deg[wid]);
    float acc0 = 0.f, acc1 = 0.f, acc2 = 0.f, acc3 = 0.f;

    const uint_t* utj = utab + 2 * lane;
#if USE_FP8
    const uint_t* xqj = xq + lane;         // word = pairs 2l, 2l+1

#define EDGE_DO(CT, NM) do {                                         \
        int c_ = (int)((CT) & 0xFFFFu);                              \
        int t_ = (int)((CT) >> 16);                                  \
        uint_t xw_ = xqj[(size_t)c_ * 64];                           \
        uint2 uw_ = *(const uint2*)(utj + (size_t)t_ * HD);          \
        float nf_ = __uint_as_float(NM);                             \
        f32x2 p0_ = __builtin_amdgcn_cvt_pk_f32_fp8((int)xw_, false);\
        f32x2 p1_ = __builtin_amdgcn_cvt_pk_f32_fp8((int)xw_, true); \
        h2 cs0_ = bch2(uw_.x), cs1_ = bch2(uw_.y);                   \
        float c0_ = (float)cs0_[0], s0_ = (float)cs0_[1];            \
        float c1_ = (float)cs1_[0], s1_ = (float)cs1_[1];            \
        float rn0_ = nf_ * p0_[0], in0_ = nf_ * p0_[1];              \
        float rn1_ = nf_ * p1_[0], in1_ = nf_ * p1_[1];              \
        acc0 = fmaf(rn0_, c0_, fmaf(in0_, s0_, acc0));               \
        acc2 = fmaf(rn0_, s0_, fmaf(-in0_, c0_, acc2));              \
        acc1 = fmaf(rn1_, c1_, fmaf(in1_, s1_, acc1));               \
        acc3 = fmaf(rn1_, s1_, fmaf(-in1_, c1_, acc3));              \
    } while (0)
#else
    const uint_t* xcj = xc + 2 * lane;     // pairs j=2l, 2l+1

#define EDGE_DO(CT, NM) do {                                 \
        int c_ = (int)((CT) & 0xFFFFu);                      \
        int t_ = (int)((CT) >> 16);                          \
        uint2 xw_ = *(const uint2*)(xcj + (size_t)c_ * HD);  \
        uint2 uw_ = *(const uint2*)(utj + (size_t)t_ * HD);  \
        float nf_ = __uint_as_float(NM);                     \
        h2 nm2_; nm2_[0] = (_Float16)nf_; nm2_[1] = nm2_[0]; \
        h2 a0_ = bch2(xw_.x) * nm2_;                         \
        h2 a1_ = bch2(xw_.y) * nm2_;                         \
        uint_t sn0_ = ((uw_.x << 16) | (uw_.x >> 16)) ^ 0x80000000u; \
        uint_t sn1_ = ((uw_.y << 16) | (uw_.y >> 16)) ^ 0x80000000u; \
        acc0 = FDOT2(a0_, bch2(uw_.x), acc0);                \
        acc2 = FDOT2(a0_, bch2(sn0_), acc2);                 \
        acc1 = FDOT2(a1_, bch2(uw_.y), acc1);                \
        acc3 = FDOT2(a1_, bch2(sn1_), acc3);                 \
    } while (0)
#endif

    int i = 0;
    for (; i + 3 < n; i += 4) {
        uint2 e0 = ent[start + i];
        uint2 e1 = ent[start + i + 1];
        uint2 e2 = ent[start + i + 2];
        uint2 e3 = ent[start + i + 3];
        EDGE_DO(e0.x, e0.y);
        EDGE_DO(e1.x, e1.y);
        EDGE_DO(e2.x, e2.y);
        EDGE_DO(e3.x, e3.y);
    }
    for (; i < n; ++i) {
        uint2 e0 = ent[start + i];
        EDGE_DO(e0.x, e0.y);
    }
#undef EDGE_DO

    uint_t* Ar = (uint_t*)(A + (size_t)(dir * MPAD + row) * DD);
    Ar[lane]      = pkh2(acc0, acc1);   // elems 2l, 2l+1
    Ar[64 + lane] = pkh2(acc2, acc3);   // elems 128+2l, 128+2l+1
}

// ---------------- MFMA GEMM: BM=128, BN=256, BK=32, counted-vmcnt dbuf -----
// out = [Ain|Aout|xc](M x 768) @ Wt^T   (1/3 pre-folded into Wt)
// Packed LDS rows (128B): A row R holds {m=R, m=R+64} x 32k; B row R holds
// {n=R, n=R+128} x 32k. 8 16B-slots/row, XOR-8 swizzled via pre-swizzled
// global source (linear LDS dest, rule-21 correct).
// Pipeline (T4): STAGE(next) then s_waitcnt vmcnt(3) — waits only for the
// PREVIOUS tile's 3 loads; the new 3 stay in flight across MFMA + barrier.
__global__ __launch_bounds__(512) void k_gemm(const ushort_t* __restrict__ Ain,
                                              const ushort_t* __restrict__ Aout,
                                              const ushort_t* __restrict__ xcf,
                                              const ushort_t* __restrict__ Wt,
                                              float* __restrict__ out) {
    __shared__ ushort_t Al[2][64 * 64];    // 8 KB per buf
    __shared__ ushort_t Bl[2][128 * 64];   // 16 KB per buf
    int tid = threadIdx.x;
    int m0 = blockIdx.x * 128;
    int lane = tid & 63, wv = tid >> 6;          // 8 waves: 2(M) x 4(N)
    int wrow = (wv >> 2) * 64, wcol = (wv & 3) * 64;
    int r = lane & 15, h = lane >> 4;            // h = k-octet 0..3

    f32x4 zero = {0.f, 0.f, 0.f, 0.f};
    f32x4 acc[4][4];
#pragma unroll
    for (int i = 0; i < 4; ++i)
#pragma unroll
        for (int j = 0; j < 4; ++j) acc[i][j] = zero;

#define STAGE(BUF, T) do {                                                     \
        int k0_ = (T) * 32;                                                    \
        const ushort_t* baseA_ = (k0_ < 256) ? Ain                             \
                                : ((k0_ < 512) ? Aout : xcf);                  \
        int kk0_ = k0_ & 255;                                                  \
        {   /* A: 512 slots, 1 per thread */                                   \
            int R_ = tid >> 3, sl_ = tid & 7, lsl_ = sl_ ^ (R_ & 7);           \
            int m_ = R_ + ((lsl_ >> 2) << 6), k8_ = (lsl_ & 3) << 3;           \
            GLOAD_LDS16(baseA_ + (size_t)(m0 + m_) * DD + kk0_ + k8_,          \
                        &Al[BUF][tid * 8]);                                    \
        }                                                                      \
        _Pragma("unroll")                                                      \
        for (int ss_ = 0; ss_ < 2; ++ss_) {  /* B: 1024 slots, 2 per thread */ \
            int s_ = tid + ss_ * 512;                                          \
            int R_ = s_ >> 3, sl_ = s_ & 7, lsl_ = sl_ ^ (R_ & 7);             \
            int n_ = R_ + ((lsl_ >> 2) << 7), k8_ = (lsl_ & 3) << 3;           \
            GLOAD_LDS16(Wt + (size_t)n_ * 768 + k0_ + k8_, &Bl[BUF][s_ * 8]);  \
        }                                                                      \
    } while (0)

    STAGE(0, 0);

    for (int t = 0; t < 24; ++t) {
        int cur = t & 1;
        if (t < 23) {
            STAGE(cur ^ 1, t + 1);   // 3 loads/thread into next buffer
            asm volatile("s_waitcnt vmcnt(3)" ::: "memory");  // prev tile landed
        } else {
            asm volatile("s_waitcnt vmcnt(0)" ::: "memory");
        }
        __builtin_amdgcn_s_barrier();            // all waves: cur buffer ready
        __builtin_amdgcn_sched_barrier(0);       // pin ds_reads after barrier
        h8 a[4], b[4];
#pragma unroll
        for (int i = 0; i < 4; ++i) {
            int mm = wrow + i * 16 + r;            // 0..127
            int R = mm & 63, half = mm >> 6;
            int sl = (half * 4 + h) ^ (R & 7);
            a[i] = *(const h8*)&Al[cur][R * 64 + sl * 8];
        }
#pragma unroll
        for (int j = 0; j < 4; ++j) {
            int nn = wcol + j * 16 + r;            // 0..255
            int R = nn & 127, half = nn >> 7;
            int sl = (half * 4 + h) ^ (R & 7);
            b[j] = *(const h8*)&Bl[cur][R * 64 + sl * 8];
        }
#pragma unroll
        for (int i = 0; i < 4; ++i)
#pragma unroll
            for (int j = 0; j < 4; ++j)
                acc[i][j] = __builtin_amdgcn_mfma_f32_16x16x32_f16(a[i], b[j], acc[i][j], 0, 0, 0);
        __builtin_amdgcn_s_barrier();  // reads of cur done before next re-stage
    }
#undef STAGE

    // C/D: col = lane&15, row = (lane>>4)*4 + reg (dtype-independent)
    int cn = lane & 15, rq = lane >> 4;
#pragma unroll
    for (int i = 0; i < 4; ++i)
#pragma unroll
        for (int j = 0; j < 4; ++j)
#pragma unroll
            for (int q = 0; q < 4; ++q) {
                int m = m0 + wrow + i * 16 + rq * 4 + q;
                if (m < N_ENT) {
                    int n = wcol + j * 16 + cn;
                    out[(size_t)m * DD + n] = acc[i][j][q];
                }
            }
}

extern "C" void kernel_launch(void* const* d_in, const int* in_sizes, int n_in,
                              void* d_out, int out_size, void* d_ws, size_t ws_size,
                              hipStream_t stream) {
    const float* x        = (const float*)d_in[0];
    const int*   ei       = (const int*)d_in[1];
    const int*   et       = (const int*)d_in[2];
    const float* rel      = (const float*)d_in[3];
    const float* w_loop   = (const float*)d_in[4];
    const float* w_in     = (const float*)d_in[5];
    const float* w_out    = (const float*)d_in[6];
    const float* w_rel    = (const float*)d_in[7];
    const float* loop_rel = (const float*)d_in[8];

    char* w = (char*)d_ws;
    ushort_t* A    = (ushort_t*)w;  w += (size_t)2 * MPAD * DD * 2;   // f16 [2][MPAD][DD]
    uint_t* xc     = (uint_t*)w;    w += (size_t)N_ENT * HD * 4;      // f16 packed pairs
    uint_t* xq     = (uint_t*)w;    w += (size_t)N_ENT * 64 * 4;      // fp8 packed pairs
    ushort_t* Wt   = (ushort_t*)w;  w += 256 * 768 * 2;
    uint_t* utab   = (uint_t*)w;    w += (size_t)N_RELS * HD * 4;
    int* deg_i     = (int*)w;       w += NK * 4;
    int* cnt       = (int*)w;       w += NK * 4;
    int* off       = (int*)w;       w += NK * 4;
    int* bsum      = (int*)w;       w += 128 * 4;
    float* dinv    = (float*)w;     w += NK * 4;
    uint2* ent     = (uint2*)w;     w += (size_t)ETOT * 8 + 64;       // +64B s_load pad
    ushort_t* Aout = A + (size_t)MPAD * DD;

    float* out     = (float*)d_out;
    float* rel_out = out + (size_t)N_ENT * DD;

    // zero deg_i + cnt (adjacent)
    hipMemsetAsync(deg_i, 0, (size_t)2 * NK * 4, stream);

    k_prep  <<<4822, 256, 0, stream>>>(x, rel, w_in, w_out, w_loop, loop_rel,
                                       w_rel, ei, xc, xq, utab, Wt, rel_out, deg_i);
    k_scan1 <<<NBLK, 256, 0, stream>>>(deg_i, off, bsum, dinv);
    k_scan2 <<<1, 128, 0, stream>>>(bsum);
    k_bucket<<<(ETOT + 255) / 256, 256, 0, stream>>>(ei, et, off, bsum, dinv, cnt, ent);
    k_gather<<<(NK + 3) / 4, 256, 0, stream>>>(ent, off, bsum, deg_i, xq, xc, utab, A);

    k_gemm  <<<MPAD / 128, 512, 0, stream>>>(A, Aout, (const ushort_t*)xc, Wt, out);
}